// Round 2
// baseline (787.485 us; speedup 1.0000x reference)
//
#include <hip/hip_runtime.h>

#define B_ 2
#define S_ 1024
#define C_ 1024
#define H_ 16
#define D_ 64
#define R_ 16
#define RK_ 32
#define FA_ 32
#define N_ (B_*S_)
#define NCH_ 16   // S_/64 chunks

// ---------------------------------------------------------------------------
// GEMM: Co[M x Nn] = A[M x K] @ W[K x Nn]  fp32, 128x128 tile, 8x8/thread.
// 2.0 flop/LDS-byte (A-read 4-bank-spread + broadcast, B contiguous) —
// balanced at the VALU/LDS crossover. ~110 VGPR -> 4 waves/SIMD.
// ---------------------------------------------------------------------------
__global__ __launch_bounds__(256) void gemm_k(const float* __restrict__ A,
                                              const float* __restrict__ W,
                                              float* __restrict__ Co,
                                              int M, int K, int Nn)
{
    __shared__ float As[16][132];   // As[k][m] (transposed)
    __shared__ float Ws[16][132];   // Ws[k][n]
    const int tid = threadIdx.x;
    const int tx = tid & 15, ty = tid >> 4;
    const int m0 = blockIdx.y << 7, n0 = blockIdx.x << 7;

    float acc[8][8] = {};
    const int ar = tid >> 1;            // A row 0..127
    const int ak = (tid & 1) << 3;      // A k 0 or 8
    const int wk = tid >> 4;            // W k 0..15
    const int wc = (tid & 15) << 3;     // W col 0..120

    const float* Ap = A + (m0 + ar)*K + ak;
    const float* Wp = W + wk*Nn + n0 + wc;

    for (int k0 = 0; k0 < K; k0 += 16) {
        float4 a0 = *reinterpret_cast<const float4*>(Ap + k0);
        float4 a1 = *reinterpret_cast<const float4*>(Ap + k0 + 4);
        float4 w0 = *reinterpret_cast<const float4*>(Wp + k0*Nn);
        float4 w1 = *reinterpret_cast<const float4*>(Wp + k0*Nn + 4);
        __syncthreads();   // previous iter's reads done before overwrite
        As[ak+0][ar] = a0.x; As[ak+1][ar] = a0.y;
        As[ak+2][ar] = a0.z; As[ak+3][ar] = a0.w;
        As[ak+4][ar] = a1.x; As[ak+5][ar] = a1.y;
        As[ak+6][ar] = a1.z; As[ak+7][ar] = a1.w;
        *reinterpret_cast<float4*>(&Ws[wk][wc])     = w0;
        *reinterpret_cast<float4*>(&Ws[wk][wc + 4]) = w1;
        __syncthreads();
        #pragma unroll
        for (int kk = 0; kk < 16; ++kk) {
            float a[8], b[8];
            *reinterpret_cast<float4*>(&a[0]) = *reinterpret_cast<const float4*>(&As[kk][ty<<3]);
            *reinterpret_cast<float4*>(&a[4]) = *reinterpret_cast<const float4*>(&As[kk][(ty<<3)+4]);
            *reinterpret_cast<float4*>(&b[0]) = *reinterpret_cast<const float4*>(&Ws[kk][tx<<3]);
            *reinterpret_cast<float4*>(&b[4]) = *reinterpret_cast<const float4*>(&Ws[kk][(tx<<3)+4]);
            #pragma unroll
            for (int i = 0; i < 8; ++i)
                #pragma unroll
                for (int j = 0; j < 8; ++j)
                    acc[i][j] += a[i]*b[j];
        }
    }
    #pragma unroll
    for (int i = 0; i < 8; ++i) {
        float* cp = Co + (m0 + (ty<<3) + i)*Nn + n0 + (tx<<3);
        *reinterpret_cast<float4*>(cp)     = make_float4(acc[i][0], acc[i][1], acc[i][2], acc[i][3]);
        *reinterpret_cast<float4*>(cp + 4) = make_float4(acc[i][4], acc[i][5], acc[i][6], acc[i][7]);
    }
}

// ---------------------------------------------------------------------------
// rule_proj: out[n] = xf[n]@si@so + reshape(rv[rid] @ (xm @ ru[rid]^T)) * g
// mode: 0 = write, 1 = rope+write (q,k), 2 = accumulate (final)
// ---------------------------------------------------------------------------
__global__ __launch_bounds__(256) void proj_k(const float* __restrict__ xin,
                                              const float* __restrict__ si,
                                              const float* __restrict__ so,
                                              const float* __restrict__ ru,
                                              const float* __restrict__ rv,
                                              const float* __restrict__ gain,
                                              const int* __restrict__ rids,
                                              float* __restrict__ outp,
                                              int mode)
{
    __shared__ float xrow[C_];
    __shared__ float tpart[8][RK_];
    __shared__ float tvec[RK_];
    __shared__ float rut[FA_*33];    // rut[a*33 + c] = ru[rid][c][a] (pad 33: conflict-free)
    __shared__ float rvs[FA_*FA_];   // rv[rid] straight
    __shared__ float xu[FA_*FA_];    // xu[b*32 + c]
    __shared__ float obuf[C_];
    const int tid = threadIdx.x;
    const int n = blockIdx.x;
    const int rid = rids[n];
    const float g = gain[rid];

    *reinterpret_cast<float4*>(&xrow[tid<<2]) =
        *reinterpret_cast<const float4*>(xin + n*C_ + (tid<<2));
    #pragma unroll
    for (int q = 0; q < 4; ++q) {
        int idx = tid + (q<<8);               // idx = c*32 + a
        rut[(idx & 31)*33 + (idx >> 5)] = ru[rid*1024 + idx];
        rvs[idx] = rv[rid*1024 + idx];
    }
    __syncthreads();
    // t = xrow @ si  (C x RK), partial per 8-slice
    {
        const int col = tid & 31, sl = tid >> 5;
        const int i0 = sl << 7;
        float a = 0.f;
        for (int i = 0; i < 128; ++i)
            a += xrow[i0 + i] * si[(i0 + i)*RK_ + col];
        tpart[sl][col] = a;
    }
    __syncthreads();
    if (tid < 32) {
        float a = 0.f;
        #pragma unroll
        for (int sl = 0; sl < 8; ++sl) a += tpart[sl][tid];
        tvec[tid] = a;
    }
    __syncthreads();
    // xu[b][c] = sum_a xrow[b*32+a] * ru[c][a]
    #pragma unroll
    for (int q = 0; q < 4; ++q) {
        int idx = tid + (q<<8);
        int bb = idx >> 5, cc = idx & 31;
        float a = 0.f;
        #pragma unroll 8
        for (int aa = 0; aa < 32; ++aa)
            a += xrow[(bb<<5) + aa] * rut[aa*33 + cc];
        xu[idx] = a;
    }
    __syncthreads();
    // obuf[m] = t@so[m] + (rv @ xu)[d][c] * g,  m = d*32 + c
    #pragma unroll
    for (int q = 0; q < 4; ++q) {
        int m = tid + (q<<8);
        int dd = m >> 5, cc = m & 31;
        float ab = 0.f;
        #pragma unroll 8
        for (int j = 0; j < RK_; ++j)
            ab += tvec[j] * so[j*C_ + m];
        float av = 0.f;
        #pragma unroll 8
        for (int bb = 0; bb < 32; ++bb)
            av += rvs[(dd<<5) + bb] * xu[(bb<<5) + cc];
        obuf[m] = ab + av * g;
    }
    __syncthreads();
    if (mode == 1) {
        const float pos = (float)(n & (S_-1));
        #pragma unroll
        for (int q = 0; q < 2; ++q) {
            int pi = tid + (q<<8);            // pair index 0..511
            int ii = pi & 31;                 // pair within head
            float f = pos * expf((float)(ii<<1) * -0.14391157f); // -ln(1e4)/64
            float sn = sinf(f), cs = cosf(f);
            float e = obuf[pi<<1], o = obuf[(pi<<1)+1];
            outp[n*C_ + (pi<<1)]     = e*cs - o*sn;
            outp[n*C_ + (pi<<1) + 1] = o*cs + e*sn;
        }
    } else if (mode == 2) {
        #pragma unroll
        for (int q = 0; q < 4; ++q) {
            int m = tid + (q<<8);
            outp[n*C_ + m] += obuf[m];
        }
    } else {
        #pragma unroll
        for (int q = 0; q < 4; ++q) {
            int m = tid + (q<<8);
            outp[n*C_ + m] = obuf[m];
        }
    }
}

// ---------------------------------------------------------------------------
// Flash attention fp32, 64x64 tiles. P-tile aliases the K^T buffer (52KB LDS).
// ---------------------------------------------------------------------------
__global__ __launch_bounds__(256) void attn_k(const float* __restrict__ qb,
                                              const float* __restrict__ kb,
                                              const float* __restrict__ vb,
                                              float* __restrict__ ctx)
{
    __shared__ float Qs[64*68];     // Qs[row*68 + d]
    __shared__ float KtPs[64*68];   // Kt[d*68 + key] during QK; Ps[row*68 + key] during PV
    __shared__ float Vs[64*68];     // Vs[key*68 + d]
    const int tid = threadIdx.x;
    const int tx = tid & 15, ty = tid >> 4;
    const int qt = blockIdx.x;
    const int b = blockIdx.y >> 4, h = blockIdx.y & 15;
    const float* qbase = qb + (b*S_)*C_ + h*64;
    const float* kbase = kb + (b*S_)*C_ + h*64;
    const float* vbase = vb + (b*S_)*C_ + h*64;

    #pragma unroll
    for (int q = 0; q < 4; ++q) {
        int idx = tid + (q<<8);
        int r = idx >> 4, d4 = (idx & 15) << 2;
        *reinterpret_cast<float4*>(&Qs[r*68 + d4]) =
            *reinterpret_cast<const float4*>(qbase + (qt*64 + r)*C_ + d4);
    }
    float acc[4][4] = {};
    float mrun[4] = {-3e38f, -3e38f, -3e38f, -3e38f};
    float lrun[4] = {};
    const int row0 = qt*64 + (ty<<2);

    for (int kt = 0; kt <= qt; ++kt) {
        __syncthreads();   // prev PV done (and Q visible on first iter)
        #pragma unroll
        for (int q = 0; q < 4; ++q) {
            int idx = tid + (q<<8);
            int r = idx >> 4, d4 = (idx & 15) << 2;
            float4 kv = *reinterpret_cast<const float4*>(kbase + (kt*64 + r)*C_ + d4);
            KtPs[(d4+0)*68 + r] = kv.x;
            KtPs[(d4+1)*68 + r] = kv.y;
            KtPs[(d4+2)*68 + r] = kv.z;
            KtPs[(d4+3)*68 + r] = kv.w;
            *reinterpret_cast<float4*>(&Vs[r*68 + d4]) =
                *reinterpret_cast<const float4*>(vbase + (kt*64 + r)*C_ + d4);
        }
        __syncthreads();
        float s[4][4] = {};
        #pragma unroll 4
        for (int d0 = 0; d0 < 64; d0 += 4) {
            float4 q4[4], k4[4];
            #pragma unroll
            for (int i = 0; i < 4; ++i)
                q4[i] = *reinterpret_cast<const float4*>(&Qs[((ty<<2)+i)*68 + d0]);
            #pragma unroll
            for (int u = 0; u < 4; ++u)
                k4[u] = *reinterpret_cast<const float4*>(&KtPs[(d0+u)*68 + (tx<<2)]);
            #pragma unroll
            for (int i = 0; i < 4; ++i) {
                float qa[4] = {q4[i].x, q4[i].y, q4[i].z, q4[i].w};
                #pragma unroll
                for (int u = 0; u < 4; ++u) {
                    s[i][0] += qa[u]*k4[u].x;
                    s[i][1] += qa[u]*k4[u].y;
                    s[i][2] += qa[u]*k4[u].z;
                    s[i][3] += qa[u]*k4[u].w;
                }
            }
        }
        __syncthreads();   // all waves done reading Kt before P overwrites it
        const int col0 = kt*64 + (tx<<2);
        #pragma unroll
        for (int i = 0; i < 4; ++i) {
            #pragma unroll
            for (int j = 0; j < 4; ++j) {
                float sv = s[i][j]*0.125f;   // 1/sqrt(64)
                if (col0 + j > row0 + i) sv = -3e38f;
                s[i][j] = sv;
            }
            float mx = fmaxf(fmaxf(s[i][0], s[i][1]), fmaxf(s[i][2], s[i][3]));
            #pragma unroll
            for (int off = 1; off < 16; off <<= 1)
                mx = fmaxf(mx, __shfl_xor(mx, off, 64));
            float mnew = fmaxf(mrun[i], mx);
            float corr = expf(mrun[i] - mnew);
            float rs = 0.f;
            #pragma unroll
            for (int j = 0; j < 4; ++j) {
                float p = expf(s[i][j] - mnew);
                s[i][j] = p;
                rs += p;
            }
            #pragma unroll
            for (int off = 1; off < 16; off <<= 1)
                rs += __shfl_xor(rs, off, 64);
            mrun[i] = mnew;
            lrun[i] = lrun[i]*corr + rs;
            acc[i][0] *= corr; acc[i][1] *= corr; acc[i][2] *= corr; acc[i][3] *= corr;
            *reinterpret_cast<float4*>(&KtPs[((ty<<2)+i)*68 + (tx<<2)]) =
                make_float4(s[i][0], s[i][1], s[i][2], s[i][3]);
        }
        __syncthreads();
        #pragma unroll 4
        for (int k0 = 0; k0 < 64; k0 += 4) {
            float4 p4[4], v4[4];
            #pragma unroll
            for (int i = 0; i < 4; ++i)
                p4[i] = *reinterpret_cast<const float4*>(&KtPs[((ty<<2)+i)*68 + k0]);
            #pragma unroll
            for (int u = 0; u < 4; ++u)
                v4[u] = *reinterpret_cast<const float4*>(&Vs[(k0+u)*68 + (tx<<2)]);
            #pragma unroll
            for (int i = 0; i < 4; ++i) {
                float pa[4] = {p4[i].x, p4[i].y, p4[i].z, p4[i].w};
                #pragma unroll
                for (int u = 0; u < 4; ++u) {
                    acc[i][0] += pa[u]*v4[u].x;
                    acc[i][1] += pa[u]*v4[u].y;
                    acc[i][2] += pa[u]*v4[u].z;
                    acc[i][3] += pa[u]*v4[u].w;
                }
            }
        }
    }
    #pragma unroll
    for (int i = 0; i < 4; ++i) {
        float inv = 1.f / lrun[i];
        *reinterpret_cast<float4*>(ctx + (b*S_ + qt*64 + (ty<<2) + i)*C_ + h*64 + (tx<<2)) =
            make_float4(acc[i][0]*inv, acc[i][1]*inv, acc[i][2]*inv, acc[i][3]*inv);
    }
}

// ---------------------------------------------------------------------------
// hier stage 1: per-(b,chunk) per-rule sums of k_val/v_val (256-ch slice each)
// ---------------------------------------------------------------------------
__global__ __launch_bounds__(256) void hchunk_k(const float* __restrict__ kvb,
                                                const int* __restrict__ rids,
                                                float* __restrict__ chk,
                                                float* __restrict__ chv)
{
    __shared__ float ks[R_*256];
    __shared__ float vs[R_*256];
    const int tid = threadIdx.x;
    const int cs = blockIdx.x, ch = blockIdx.y, b = blockIdx.z;
    const int c = (cs<<8) + tid;
    #pragma unroll
    for (int u = 0; u < R_; ++u) { ks[(u<<8) + tid] = 0.f; vs[(u<<8) + tid] = 0.f; }
    const int* rp = rids + b*S_ + (ch<<6);
    const float* kvp = kvb + (b*S_ + (ch<<6))*2048 + c;
    for (int s2 = 0; s2 < 64; ++s2) {
        const int u = rp[s2];
        ks[(u<<8) + tid] += kvp[0];
        vs[(u<<8) + tid] += kvp[1024];
        kvp += 2048;
    }
    #pragma unroll
    for (int u = 0; u < R_; ++u) {
        chk[((b*NCH_ + ch)*R_ + u)*C_ + c] = ks[(u<<8) + tid];
        chv[((b*NCH_ + ch)*R_ + u)*C_ + c] = vs[(u<<8) + tid];
    }
}

// hier stage 2: in-place exclusive scan over chunks, per (b, rule, channel)
__global__ __launch_bounds__(256) void hscan_k(float* __restrict__ chk,
                                               float* __restrict__ chv)
{
    const int idx = blockIdx.x*256 + threadIdx.x;   // B*R*C = 32768
    const int b = idx >> 14;
    const int rc = idx & 16383;
    const int base = b*(NCH_*R_*C_) + rc;
    float rk = 0.f, rv2 = 0.f;
    for (int ch = 0; ch < NCH_; ++ch) {
        const int o = base + ch*(R_*C_);
        float tk = chk[o]; chk[o] = rk; rk += tk;
        float tv = chv[o]; chv[o] = rv2; rv2 += tv;
    }
}

// hier stage 3a: per-token per-rule partial logits (half the channels/block)
__global__ __launch_bounds__(512) void hweights_k(const float* __restrict__ chk,
                                                  const float* __restrict__ kvb,
                                                  const float* __restrict__ qv,
                                                  const int* __restrict__ rids,
                                                  float* __restrict__ lgp)
{
    __shared__ float ksum[R_*512];
    __shared__ int cnt[R_];
    const int tid = threadIdx.x;
    const int half = blockIdx.x, ch = blockIdx.y, b = blockIdx.z;
    const int c0 = half << 9;
    #pragma unroll
    for (int u = 0; u < R_; ++u)
        ksum[(u<<9) + tid] = chk[((b*NCH_ + ch)*R_ + u)*C_ + c0 + tid];
    if (tid < R_) cnt[tid] = 0;
    __syncthreads();
    for (int t = tid; t < ch*64; t += 512)
        atomicAdd(&cnt[rids[b*S_ + t]], 1);
    __syncthreads();
    const int wv = tid >> 6, ln = tid & 63;   // 8 waves, 2 rules each
    for (int s = 0; s < 64; ++s) {
        const int row = b*S_ + (ch<<6) + s;
        const int u = rids[row];
        ksum[(u<<9) + tid] += kvb[row*2048 + c0 + tid];
        if (tid == 0) cnt[u] += 1;
        __syncthreads();
        #pragma unroll
        for (int uu = 0; uu < 2; ++uu) {
            const int ur = (wv<<1) + uu;
            float part = 0.f;
            #pragma unroll
            for (int j = 0; j < 8; ++j) {
                int c = ln + (j<<6);
                part += qv[row*C_ + c0 + c] * ksum[(ur<<9) + c];
            }
            #pragma unroll
            for (int off = 1; off < 64; off <<= 1)
                part += __shfl_xor(part, off, 64);
            if (ln == 0)
                lgp[(row<<5) + (ur<<1) + half] =
                    part * 0.03125f / (float)(cnt[ur] > 0 ? cnt[ur] : 1);
        }
        __syncthreads();
    }
}

// hier stage 3b: combine halves + softmax over 16 rules
__global__ __launch_bounds__(256) void wfinal_k(const float* __restrict__ lgp,
                                                float* __restrict__ wout)
{
    const int row = blockIdx.x*256 + threadIdx.x;
    float lg[R_];
    float mx = -3e38f;
    #pragma unroll
    for (int u = 0; u < R_; ++u) {
        lg[u] = lgp[(row<<5) + (u<<1)] + lgp[(row<<5) + (u<<1) + 1];
        mx = fmaxf(mx, lg[u]);
    }
    float sm = 0.f;
    #pragma unroll
    for (int u = 0; u < R_; ++u) { lg[u] = expf(lg[u] - mx); sm += lg[u]; }
    const float inv = 1.f / sm;
    #pragma unroll
    for (int u = 0; u < R_; ++u)
        wout[(row<<4) + u] = lg[u] * inv;
}

// hier stage 3c: out = gate * sum_u w[u] * v_mean[u]   (writes d_out with =)
__global__ __launch_bounds__(512) void hmix_k(const float* __restrict__ chv,
                                              const float* __restrict__ kvb,
                                              const int* __restrict__ rids,
                                              const float* __restrict__ wout,
                                              const float* __restrict__ gate,
                                              float* __restrict__ outp)
{
    __shared__ float vsum[R_*512];
    __shared__ int cnt[R_];
    __shared__ float rcq[R_];
    __shared__ float wsh[R_];
    const int tid = threadIdx.x;
    const int half = blockIdx.x, ch = blockIdx.y, b = blockIdx.z;
    const int c0 = half << 9;
    #pragma unroll
    for (int u = 0; u < R_; ++u)
        vsum[(u<<9) + tid] = chv[((b*NCH_ + ch)*R_ + u)*C_ + c0 + tid];
    if (tid < R_) cnt[tid] = 0;
    __syncthreads();
    for (int t = tid; t < ch*64; t += 512)
        atomicAdd(&cnt[rids[b*S_ + t]], 1);
    const float gt = gate[c0 + tid];
    __syncthreads();
    for (int s = 0; s < 64; ++s) {
        const int row = b*S_ + (ch<<6) + s;
        const int u = rids[row];
        vsum[(u<<9) + tid] += kvb[row*2048 + 1024 + c0 + tid];
        if (tid == 0) cnt[u] += 1;
        __syncthreads();
        if (tid < R_) {
            rcq[tid] = 1.f / (float)(cnt[tid] > 0 ? cnt[tid] : 1);
            wsh[tid] = wout[(row<<4) + tid];
        }
        __syncthreads();
        float a = 0.f;
        #pragma unroll
        for (int u2 = 0; u2 < R_; ++u2)
            a += wsh[u2] * rcq[u2] * vsum[(u2<<9) + tid];
        outp[row*C_ + c0 + tid] = a * gt;
        __syncthreads();
    }
}

// ---------------------------------------------------------------------------
extern "C" void kernel_launch(void* const* d_in, const int* in_sizes, int n_in,
                              void* d_out, int out_size, void* d_ws, size_t ws_size,
                              hipStream_t stream) {
    (void)in_sizes; (void)n_in; (void)out_size; (void)ws_size;
    const float* x    = (const float*)d_in[0];
    const float* sin_ = (const float*)d_in[1];
    const float* sout = (const float*)d_in[2];
    const float* rU   = (const float*)d_in[3];
    const float* rV   = (const float*)d_in[4];
    const float* rG   = (const float*)d_in[5];
    const float* wq   = (const float*)d_in[6];
    const float* wkv  = (const float*)d_in[7];
    const float* gate = (const float*)d_in[8];
    const int*   rids = (const int*)d_in[9];
    float* out = (float*)d_out;
    float* ws  = (float*)d_ws;

    // ---- hier phase buffers (freed after hmix) ----
    float* QV   = ws;             // N*C           q_val = x@wq
    float* KV   = ws + 2097152;   // N*2C          [k_val | v_val] = x@wkv
    float* CHK  = ws + 6291456;   // B*16*R*C      chunk prefix sums (k)
    float* CHV  = ws + 6815744;   //               chunk prefix sums (v)
    float* WOUT = ws + 7340032;   // N*R           softmax weights
    float* LGP  = ws + 7372800;   // N*R*2         partial logits
    // ---- attention phase buffers (reuse same memory) ----
    float* qb   = ws;             // N*C
    float* kb   = ws + 2097152;   // N*C
    float* vbuf = ws + 4194304;   // N*C
    float* ctxb = ws + 6291456;   // N*C

    // _hier
    gemm_k<<<dim3(8,  16), 256, 0, stream>>>(x, wq,  QV, N_, C_, C_);
    gemm_k<<<dim3(16, 16), 256, 0, stream>>>(x, wkv, KV, N_, C_, 2*C_);
    hchunk_k<<<dim3(4, NCH_, B_), 256, 0, stream>>>(KV, rids, CHK, CHV);
    hscan_k<<<dim3(128), 256, 0, stream>>>(CHK, CHV);
    hweights_k<<<dim3(2, NCH_, B_), 512, 0, stream>>>(CHK, KV, QV, rids, LGP);
    wfinal_k<<<dim3(8), 256, 0, stream>>>(LGP, WOUT);
    hmix_k<<<dim3(2, NCH_, B_), 512, 0, stream>>>(CHV, KV, rids, WOUT, gate, out);

    // q/k/v rule projections (+ fused RoPE on q,k)
    proj_k<<<dim3(N_), 256, 0, stream>>>(x, sin_,       sout,       rU,       rV,       rG,    rids, qb,   1);
    proj_k<<<dim3(N_), 256, 0, stream>>>(x, sin_+32768, sout+32768, rU+16384, rV+16384, rG+16, rids, kb,   1);
    proj_k<<<dim3(N_), 256, 0, stream>>>(x, sin_+65536, sout+65536, rU+32768, rV+32768, rG+32, rids, vbuf, 0);

    // causal attention
    attn_k<<<dim3(16, 32), 256, 0, stream>>>(qb, kb, vbuf, ctxb);

    // output rule projection, accumulated onto hier result
    proj_k<<<dim3(N_), 256, 0, stream>>>(ctxb, sin_+98304, sout+98304, rU+49152, rV+49152, rG+48, rids, out, 2);
}

// Round 3
// 686.609 us; speedup vs baseline: 1.1469x; 1.1469x over previous
//
#include <hip/hip_runtime.h>

#define B_ 2
#define S_ 1024
#define C_ 1024
#define H_ 16
#define D_ 64
#define R_ 16
#define RK_ 32
#define FA_ 32
#define N_ (B_*S_)
#define NCH_ 16   // S_/64 chunks

typedef __attribute__((ext_vector_type(8))) short bf16x8;
typedef __attribute__((ext_vector_type(4))) float f32x4;
#define MFMA_BF16(A,B,C) __builtin_amdgcn_mfma_f32_16x16x32_bf16(A,B,C,0,0,0)

__device__ inline unsigned short f2bf(float x) {
    unsigned u = __float_as_uint(x);
    return (unsigned short)((u + 0x7FFFu + ((u >> 16) & 1u)) >> 16);   // RNE
}
__device__ inline unsigned pack2(float a, float b) {
    return (unsigned)f2bf(a) | ((unsigned)f2bf(b) << 16);
}

// ---------------------------------------------------------------------------
// GEMM: Co[M x Nn] = A[M x K] @ W[K x Nn]  fp32, 128x128 tile, 8x8/thread.
// ---------------------------------------------------------------------------
__global__ __launch_bounds__(256) void gemm_k(const float* __restrict__ A,
                                              const float* __restrict__ W,
                                              float* __restrict__ Co,
                                              int M, int K, int Nn)
{
    __shared__ float As[16][132];   // As[k][m] (transposed)
    __shared__ float Ws[16][132];   // Ws[k][n]
    const int tid = threadIdx.x;
    const int tx = tid & 15, ty = tid >> 4;
    const int m0 = blockIdx.y << 7, n0 = blockIdx.x << 7;

    float acc[8][8] = {};
    const int ar = tid >> 1;            // A row 0..127
    const int ak = (tid & 1) << 3;      // A k 0 or 8
    const int wk = tid >> 4;            // W k 0..15
    const int wc = (tid & 15) << 3;     // W col 0..120

    const float* Ap = A + (m0 + ar)*K + ak;
    const float* Wp = W + wk*Nn + n0 + wc;

    for (int k0 = 0; k0 < K; k0 += 16) {
        float4 a0 = *reinterpret_cast<const float4*>(Ap + k0);
        float4 a1 = *reinterpret_cast<const float4*>(Ap + k0 + 4);
        float4 w0 = *reinterpret_cast<const float4*>(Wp + k0*Nn);
        float4 w1 = *reinterpret_cast<const float4*>(Wp + k0*Nn + 4);
        __syncthreads();
        As[ak+0][ar] = a0.x; As[ak+1][ar] = a0.y;
        As[ak+2][ar] = a0.z; As[ak+3][ar] = a0.w;
        As[ak+4][ar] = a1.x; As[ak+5][ar] = a1.y;
        As[ak+6][ar] = a1.z; As[ak+7][ar] = a1.w;
        *reinterpret_cast<float4*>(&Ws[wk][wc])     = w0;
        *reinterpret_cast<float4*>(&Ws[wk][wc + 4]) = w1;
        __syncthreads();
        #pragma unroll
        for (int kk = 0; kk < 16; ++kk) {
            float a[8], b[8];
            *reinterpret_cast<float4*>(&a[0]) = *reinterpret_cast<const float4*>(&As[kk][ty<<3]);
            *reinterpret_cast<float4*>(&a[4]) = *reinterpret_cast<const float4*>(&As[kk][(ty<<3)+4]);
            *reinterpret_cast<float4*>(&b[0]) = *reinterpret_cast<const float4*>(&Ws[kk][tx<<3]);
            *reinterpret_cast<float4*>(&b[4]) = *reinterpret_cast<const float4*>(&Ws[kk][(tx<<3)+4]);
            #pragma unroll
            for (int i = 0; i < 8; ++i)
                #pragma unroll
                for (int j = 0; j < 8; ++j)
                    acc[i][j] += a[i]*b[j];
        }
    }
    #pragma unroll
    for (int i = 0; i < 8; ++i) {
        float* cp = Co + (m0 + (ty<<3) + i)*Nn + n0 + (tx<<3);
        *reinterpret_cast<float4*>(cp)     = make_float4(acc[i][0], acc[i][1], acc[i][2], acc[i][3]);
        *reinterpret_cast<float4*>(cp + 4) = make_float4(acc[i][4], acc[i][5], acc[i][6], acc[i][7]);
    }
}

// ---------------------------------------------------------------------------
// rule_proj (unchanged, verified passing)
// ---------------------------------------------------------------------------
__global__ __launch_bounds__(256) void proj_k(const float* __restrict__ xin,
                                              const float* __restrict__ si,
                                              const float* __restrict__ so,
                                              const float* __restrict__ ru,
                                              const float* __restrict__ rv,
                                              const float* __restrict__ gain,
                                              const int* __restrict__ rids,
                                              float* __restrict__ outp,
                                              int mode)
{
    __shared__ float xrow[C_];
    __shared__ float tpart[8][RK_];
    __shared__ float tvec[RK_];
    __shared__ float rut[FA_*33];
    __shared__ float rvs[FA_*FA_];
    __shared__ float xu[FA_*FA_];
    __shared__ float obuf[C_];
    const int tid = threadIdx.x;
    const int n = blockIdx.x;
    const int rid = rids[n];
    const float g = gain[rid];

    *reinterpret_cast<float4*>(&xrow[tid<<2]) =
        *reinterpret_cast<const float4*>(xin + n*C_ + (tid<<2));
    #pragma unroll
    for (int q = 0; q < 4; ++q) {
        int idx = tid + (q<<8);
        rut[(idx & 31)*33 + (idx >> 5)] = ru[rid*1024 + idx];
        rvs[idx] = rv[rid*1024 + idx];
    }
    __syncthreads();
    {
        const int col = tid & 31, sl = tid >> 5;
        const int i0 = sl << 7;
        float a = 0.f;
        for (int i = 0; i < 128; ++i)
            a += xrow[i0 + i] * si[(i0 + i)*RK_ + col];
        tpart[sl][col] = a;
    }
    __syncthreads();
    if (tid < 32) {
        float a = 0.f;
        #pragma unroll
        for (int sl = 0; sl < 8; ++sl) a += tpart[sl][tid];
        tvec[tid] = a;
    }
    __syncthreads();
    #pragma unroll
    for (int q = 0; q < 4; ++q) {
        int idx = tid + (q<<8);
        int bb = idx >> 5, cc = idx & 31;
        float a = 0.f;
        #pragma unroll 8
        for (int aa = 0; aa < 32; ++aa)
            a += xrow[(bb<<5) + aa] * rut[aa*33 + cc];
        xu[idx] = a;
    }
    __syncthreads();
    #pragma unroll
    for (int q = 0; q < 4; ++q) {
        int m = tid + (q<<8);
        int dd = m >> 5, cc = m & 31;
        float ab = 0.f;
        #pragma unroll 8
        for (int j = 0; j < RK_; ++j)
            ab += tvec[j] * so[j*C_ + m];
        float av = 0.f;
        #pragma unroll 8
        for (int bb = 0; bb < 32; ++bb)
            av += rvs[(dd<<5) + bb] * xu[(bb<<5) + cc];
        obuf[m] = ab + av * g;
    }
    __syncthreads();
    if (mode == 1) {
        const float pos = (float)(n & (S_-1));
        #pragma unroll
        for (int q = 0; q < 2; ++q) {
            int pi = tid + (q<<8);
            int ii = pi & 31;
            float f = pos * expf((float)(ii<<1) * -0.14391157f);
            float sn = sinf(f), cs = cosf(f);
            float e = obuf[pi<<1], o = obuf[(pi<<1)+1];
            outp[n*C_ + (pi<<1)]     = e*cs - o*sn;
            outp[n*C_ + (pi<<1) + 1] = o*cs + e*sn;
        }
    } else if (mode == 2) {
        #pragma unroll
        for (int q = 0; q < 4; ++q) {
            int m = tid + (q<<8);
            outp[n*C_ + m] += obuf[m];
        }
    } else {
        #pragma unroll
        for (int q = 0; q < 4; ++q) {
            int m = tid + (q<<8);
            outp[n*C_ + m] = obuf[m];
        }
    }
}

// ---------------------------------------------------------------------------
// Flash attention: bf16 MFMA (16x16x32), fp32 softmax/accum.
// 4 waves/block; wave w owns q-rows [qt*64+w*16, +16).
// A/B frag: elem16 = lane&15, k = 8*(lane>>4)+j (contiguous b128 loads).
// C/D frag: col = lane&15, row = (lane>>4)*4 + reg  [m89-verified].
// ---------------------------------------------------------------------------
__global__ __launch_bounds__(256) void attn_k(const float* __restrict__ qb,
                                              const float* __restrict__ kb,
                                              const float* __restrict__ vb,
                                              float* __restrict__ ctx)
{
    __shared__ unsigned short Ks[64*72];   // [key][d]  stride 72 (2-way conflicts: free)
    __shared__ unsigned short Vt[64*72];   // [d][key]  stride 72
    __shared__ unsigned short Ps[64*72];   // [qrow][key], per-wave 16-row slices
    const int tid = threadIdx.x;
    const int lane = tid & 63, w = tid >> 6;
    const int lm = lane & 15, lg = lane >> 4;
    const int qt = blockIdx.x;
    const int b = blockIdx.y >> 4, h = blockIdx.y & 15;
    const float* qbase = qb + (size_t)(b*S_)*C_ + h*64;
    const float* kbase = kb + (size_t)(b*S_)*C_ + h*64;
    const float* vbase = vb + (size_t)(b*S_)*C_ + h*64;

    // Q fragments (A operand), converted once
    bf16x8 qf[2];
    {
        const int qrow = qt*64 + w*16 + lm;
        #pragma unroll
        for (int kd = 0; kd < 2; ++kd) {
            const float* qp = qbase + (size_t)qrow*C_ + kd*32 + lg*8;
            float4 f0 = *reinterpret_cast<const float4*>(qp);
            float4 f1 = *reinterpret_cast<const float4*>(qp + 4);
            unsigned u0 = pack2(f0.x, f0.y), u1 = pack2(f0.z, f0.w);
            unsigned u2 = pack2(f1.x, f1.y), u3 = pack2(f1.z, f1.w);
            bf16x8 t;
            t[0] = (short)(u0 & 0xFFFF); t[1] = (short)(u0 >> 16);
            t[2] = (short)(u1 & 0xFFFF); t[3] = (short)(u1 >> 16);
            t[4] = (short)(u2 & 0xFFFF); t[5] = (short)(u2 >> 16);
            t[6] = (short)(u3 & 0xFFFF); t[7] = (short)(u3 >> 16);
            qf[kd] = t;
        }
    }

    f32x4 oacc0 = {0.f,0.f,0.f,0.f}, oacc1 = {0.f,0.f,0.f,0.f};
    f32x4 oacc2 = {0.f,0.f,0.f,0.f}, oacc3 = {0.f,0.f,0.f,0.f};
    float mrun[4] = {-3e38f,-3e38f,-3e38f,-3e38f};
    float lrun[4] = {0.f,0.f,0.f,0.f};

    const int skey = tid >> 2, sd = (tid & 3) << 4;   // K staging: coalesced rows
    const int vkey = lane,     vd = w << 4;           // V staging: lane-per-key (conflict-free writes)

    for (int kt = 0; kt <= qt; ++kt) {
        __syncthreads();   // previous iteration's Ks/Vt reads complete
        {   // stage K -> Ks[key][d] bf16
            const float* kp = kbase + (size_t)(kt*64 + skey)*C_ + sd;
            float4 k0 = *reinterpret_cast<const float4*>(kp);
            float4 k1 = *reinterpret_cast<const float4*>(kp + 4);
            float4 k2 = *reinterpret_cast<const float4*>(kp + 8);
            float4 k3 = *reinterpret_cast<const float4*>(kp + 12);
            uint4 p0 = { pack2(k0.x,k0.y), pack2(k0.z,k0.w), pack2(k1.x,k1.y), pack2(k1.z,k1.w) };
            uint4 p1 = { pack2(k2.x,k2.y), pack2(k2.z,k2.w), pack2(k3.x,k3.y), pack2(k3.z,k3.w) };
            *reinterpret_cast<uint4*>(&Ks[skey*72 + sd])     = p0;
            *reinterpret_cast<uint4*>(&Ks[skey*72 + sd + 8]) = p1;
        }
        {   // stage V -> Vt[d][key] bf16 (transposed)
            const float* vp = vbase + (size_t)(kt*64 + vkey)*C_ + vd;
            float4 v0 = *reinterpret_cast<const float4*>(vp);
            float4 v1 = *reinterpret_cast<const float4*>(vp + 4);
            float4 v2 = *reinterpret_cast<const float4*>(vp + 8);
            float4 v3 = *reinterpret_cast<const float4*>(vp + 12);
            float vv[16] = {v0.x,v0.y,v0.z,v0.w, v1.x,v1.y,v1.z,v1.w,
                            v2.x,v2.y,v2.z,v2.w, v3.x,v3.y,v3.z,v3.w};
            #pragma unroll
            for (int j = 0; j < 16; ++j)
                Vt[(vd + j)*72 + vkey] = f2bf(vv[j]);
        }
        __syncthreads();

        // ---- S = Q K^T (per wave: 16 rows x 64 keys, 4 col-tiles) ----
        f32x4 sa[4];
        #pragma unroll
        for (int T = 0; T < 4; ++T) {
            f32x4 z = {0.f,0.f,0.f,0.f};
            #pragma unroll
            for (int kd = 0; kd < 2; ++kd) {
                bf16x8 kf = *reinterpret_cast<const bf16x8*>(&Ks[(T*16 + lm)*72 + kd*32 + lg*8]);
                z = MFMA_BF16(qf[kd], kf, z);
            }
            sa[T] = z;
        }

        // ---- online softmax (fp32) ----
        const bool diag = (kt == qt);
        float sv[4][4], pv[4][4];
        #pragma unroll
        for (int T = 0; T < 4; ++T)
            #pragma unroll
            for (int r = 0; r < 4; ++r) {
                float val = sa[T][r] * 0.125f;
                if (diag && (T*16 + lm > w*16 + lg*4 + r)) val = -3e38f;
                sv[T][r] = val;
            }
        #pragma unroll
        for (int r = 0; r < 4; ++r) {
            float mrow = fmaxf(fmaxf(sv[0][r], sv[1][r]), fmaxf(sv[2][r], sv[3][r]));
            mrow = fmaxf(mrow, __shfl_xor(mrow, 1, 64));
            mrow = fmaxf(mrow, __shfl_xor(mrow, 2, 64));
            mrow = fmaxf(mrow, __shfl_xor(mrow, 4, 64));
            mrow = fmaxf(mrow, __shfl_xor(mrow, 8, 64));
            float mnew = fmaxf(mrun[r], mrow);
            float corr = expf(mrun[r] - mnew);
            float rs = 0.f;
            #pragma unroll
            for (int T = 0; T < 4; ++T) {
                float p = expf(sv[T][r] - mnew);
                pv[T][r] = p;
                rs += p;
            }
            rs += __shfl_xor(rs, 1, 64);
            rs += __shfl_xor(rs, 2, 64);
            rs += __shfl_xor(rs, 4, 64);
            rs += __shfl_xor(rs, 8, 64);
            mrun[r] = mnew;
            lrun[r] = lrun[r]*corr + rs;
            oacc0[r] *= corr; oacc1[r] *= corr; oacc2[r] *= corr; oacc3[r] *= corr;
        }

        // ---- P -> LDS (per-wave rows; same-wave RAW, fence below) ----
        #pragma unroll
        for (int T = 0; T < 4; ++T)
            #pragma unroll
            for (int r = 0; r < 4; ++r)
                Ps[(w*16 + lg*4 + r)*72 + T*16 + lm] = f2bf(pv[T][r]);
        asm volatile("s_waitcnt lgkmcnt(0)" ::: "memory");
        __builtin_amdgcn_sched_barrier(0);

        // ---- O += P V ----
        bf16x8 pf0 = *reinterpret_cast<const bf16x8*>(&Ps[(w*16 + lm)*72 + 0*32 + lg*8]);
        bf16x8 pf1 = *reinterpret_cast<const bf16x8*>(&Ps[(w*16 + lm)*72 + 1*32 + lg*8]);
        {
            bf16x8 vf;
            vf = *reinterpret_cast<const bf16x8*>(&Vt[(0*16 + lm)*72 + 0*32 + lg*8]);
            oacc0 = MFMA_BF16(pf0, vf, oacc0);
            vf = *reinterpret_cast<const bf16x8*>(&Vt[(0*16 + lm)*72 + 1*32 + lg*8]);
            oacc0 = MFMA_BF16(pf1, vf, oacc0);
            vf = *reinterpret_cast<const bf16x8*>(&Vt[(1*16 + lm)*72 + 0*32 + lg*8]);
            oacc1 = MFMA_BF16(pf0, vf, oacc1);
            vf = *reinterpret_cast<const bf16x8*>(&Vt[(1*16 + lm)*72 + 1*32 + lg*8]);
            oacc1 = MFMA_BF16(pf1, vf, oacc1);
            vf = *reinterpret_cast<const bf16x8*>(&Vt[(2*16 + lm)*72 + 0*32 + lg*8]);
            oacc2 = MFMA_BF16(pf0, vf, oacc2);
            vf = *reinterpret_cast<const bf16x8*>(&Vt[(2*16 + lm)*72 + 1*32 + lg*8]);
            oacc2 = MFMA_BF16(pf1, vf, oacc2);
            vf = *reinterpret_cast<const bf16x8*>(&Vt[(3*16 + lm)*72 + 0*32 + lg*8]);
            oacc3 = MFMA_BF16(pf0, vf, oacc3);
            vf = *reinterpret_cast<const bf16x8*>(&Vt[(3*16 + lm)*72 + 1*32 + lg*8]);
            oacc3 = MFMA_BF16(pf1, vf, oacc3);
        }
    }

    // ---- epilogue: O / l ----
    #pragma unroll
    for (int r = 0; r < 4; ++r) {
        float inv = 1.f / lrun[r];
        float* cp = ctx + (size_t)(b*S_ + qt*64 + w*16 + lg*4 + r)*C_ + h*64;
        cp[0*16 + lm] = oacc0[r]*inv;
        cp[1*16 + lm] = oacc1[r]*inv;
        cp[2*16 + lm] = oacc2[r]*inv;
        cp[3*16 + lm] = oacc3[r]*inv;
    }
}

// ---------------------------------------------------------------------------
// hier stages (unchanged, verified passing)
// ---------------------------------------------------------------------------
__global__ __launch_bounds__(256) void hchunk_k(const float* __restrict__ kvb,
                                                const int* __restrict__ rids,
                                                float* __restrict__ chk,
                                                float* __restrict__ chv)
{
    __shared__ float ks[R_*256];
    __shared__ float vs[R_*256];
    const int tid = threadIdx.x;
    const int cs = blockIdx.x, ch = blockIdx.y, b = blockIdx.z;
    const int c = (cs<<8) + tid;
    #pragma unroll
    for (int u = 0; u < R_; ++u) { ks[(u<<8) + tid] = 0.f; vs[(u<<8) + tid] = 0.f; }
    const int* rp = rids + b*S_ + (ch<<6);
    const float* kvp = kvb + (b*S_ + (ch<<6))*2048 + c;
    for (int s2 = 0; s2 < 64; ++s2) {
        const int u = rp[s2];
        ks[(u<<8) + tid] += kvp[0];
        vs[(u<<8) + tid] += kvp[1024];
        kvp += 2048;
    }
    #pragma unroll
    for (int u = 0; u < R_; ++u) {
        chk[((b*NCH_ + ch)*R_ + u)*C_ + c] = ks[(u<<8) + tid];
        chv[((b*NCH_ + ch)*R_ + u)*C_ + c] = vs[(u<<8) + tid];
    }
}

__global__ __launch_bounds__(256) void hscan_k(float* __restrict__ chk,
                                               float* __restrict__ chv)
{
    const int idx = blockIdx.x*256 + threadIdx.x;
    const int b = idx >> 14;
    const int rc = idx & 16383;
    const int base = b*(NCH_*R_*C_) + rc;
    float rk = 0.f, rv2 = 0.f;
    for (int ch = 0; ch < NCH_; ++ch) {
        const int o = base + ch*(R_*C_);
        float tk = chk[o]; chk[o] = rk; rk += tk;
        float tv = chv[o]; chv[o] = rv2; rv2 += tv;
    }
}

__global__ __launch_bounds__(512) void hweights_k(const float* __restrict__ chk,
                                                  const float* __restrict__ kvb,
                                                  const float* __restrict__ qv,
                                                  const int* __restrict__ rids,
                                                  float* __restrict__ lgp)
{
    __shared__ float ksum[R_*512];
    __shared__ int cnt[R_];
    const int tid = threadIdx.x;
    const int half = blockIdx.x, ch = blockIdx.y, b = blockIdx.z;
    const int c0 = half << 9;
    #pragma unroll
    for (int u = 0; u < R_; ++u)
        ksum[(u<<9) + tid] = chk[((b*NCH_ + ch)*R_ + u)*C_ + c0 + tid];
    if (tid < R_) cnt[tid] = 0;
    __syncthreads();
    for (int t = tid; t < ch*64; t += 512)
        atomicAdd(&cnt[rids[b*S_ + t]], 1);
    __syncthreads();
    const int wv = tid >> 6, ln = tid & 63;
    for (int s = 0; s < 64; ++s) {
        const int row = b*S_ + (ch<<6) + s;
        const int u = rids[row];
        ksum[(u<<9) + tid] += kvb[row*2048 + c0 + tid];
        if (tid == 0) cnt[u] += 1;
        __syncthreads();
        #pragma unroll
        for (int uu = 0; uu < 2; ++uu) {
            const int ur = (wv<<1) + uu;
            float part = 0.f;
            #pragma unroll
            for (int j = 0; j < 8; ++j) {
                int c = ln + (j<<6);
                part += qv[row*C_ + c0 + c] * ksum[(ur<<9) + c];
            }
            #pragma unroll
            for (int off = 1; off < 64; off <<= 1)
                part += __shfl_xor(part, off, 64);
            if (ln == 0)
                lgp[(row<<5) + (ur<<1) + half] =
                    part * 0.03125f / (float)(cnt[ur] > 0 ? cnt[ur] : 1);
        }
        __syncthreads();
    }
}

__global__ __launch_bounds__(256) void wfinal_k(const float* __restrict__ lgp,
                                                float* __restrict__ wout)
{
    const int row = blockIdx.x*256 + threadIdx.x;
    float lg[R_];
    float mx = -3e38f;
    #pragma unroll
    for (int u = 0; u < R_; ++u) {
        lg[u] = lgp[(row<<5) + (u<<1)] + lgp[(row<<5) + (u<<1) + 1];
        mx = fmaxf(mx, lg[u]);
    }
    float sm = 0.f;
    #pragma unroll
    for (int u = 0; u < R_; ++u) { lg[u] = expf(lg[u] - mx); sm += lg[u]; }
    const float inv = 1.f / sm;
    #pragma unroll
    for (int u = 0; u < R_; ++u)
        wout[(row<<4) + u] = lg[u] * inv;
}

__global__ __launch_bounds__(512) void hmix_k(const float* __restrict__ chv,
                                              const float* __restrict__ kvb,
                                              const int* __restrict__ rids,
                                              const float* __restrict__ wout,
                                              const float* __restrict__ gate,
                                              float* __restrict__ outp)
{
    __shared__ float vsum[R_*512];
    __shared__ int cnt[R_];
    __shared__ float rcq[R_];
    __shared__ float wsh[R_];
    const int tid = threadIdx.x;
    const int half = blockIdx.x, ch = blockIdx.y, b = blockIdx.z;
    const int c0 = half << 9;
    #pragma unroll
    for (int u = 0; u < R_; ++u)
        vsum[(u<<9) + tid] = chv[((b*NCH_ + ch)*R_ + u)*C_ + c0 + tid];
    if (tid < R_) cnt[tid] = 0;
    __syncthreads();
    for (int t = tid; t < ch*64; t += 512)
        atomicAdd(&cnt[rids[b*S_ + t]], 1);
    const float gt = gate[c0 + tid];
    __syncthreads();
    for (int s = 0; s < 64; ++s) {
        const int row = b*S_ + (ch<<6) + s;
        const int u = rids[row];
        vsum[(u<<9) + tid] += kvb[row*2048 + 1024 + c0 + tid];
        if (tid == 0) cnt[u] += 1;
        __syncthreads();
        if (tid < R_) {
            rcq[tid] = 1.f / (float)(cnt[tid] > 0 ? cnt[tid] : 1);
            wsh[tid] = wout[(row<<4) + tid];
        }
        __syncthreads();
        float a = 0.f;
        #pragma unroll
        for (int u2 = 0; u2 < R_; ++u2)
            a += wsh[u2] * rcq[u2] * vsum[(u2<<9) + tid];
        outp[row*C_ + c0 + tid] = a * gt;
        __syncthreads();
    }
}

// ---------------------------------------------------------------------------
extern "C" void kernel_launch(void* const* d_in, const int* in_sizes, int n_in,
                              void* d_out, int out_size, void* d_ws, size_t ws_size,
                              hipStream_t stream) {
    (void)in_sizes; (void)n_in; (void)out_size; (void)ws_size;
    const float* x    = (const float*)d_in[0];
    const float* sin_ = (const float*)d_in[1];
    const float* sout = (const float*)d_in[2];
    const float* rU   = (const float*)d_in[3];
    const float* rV   = (const float*)d_in[4];
    const float* rG   = (const float*)d_in[5];
    const float* wq   = (const float*)d_in[6];
    const float* wkv  = (const float*)d_in[7];
    const float* gate = (const float*)d_in[8];
    const int*   rids = (const int*)d_in[9];
    float* out = (float*)d_out;
    float* ws  = (float*)d_ws;

    float* QV   = ws;             // N*C
    float* KV   = ws + 2097152;   // N*2C
    float* CHK  = ws + 6291456;
    float* CHV  = ws + 6815744;
    float* WOUT = ws + 7340032;
    float* LGP  = ws + 7372800;
    float* qb   = ws;             // N*C   (reuse after hier)
    float* kb   = ws + 2097152;
    float* vbuf = ws + 4194304;
    float* ctxb = ws + 6291456;

    // _hier
    gemm_k<<<dim3(8,  16), 256, 0, stream>>>(x, wq,  QV, N_, C_, C_);
    gemm_k<<<dim3(16, 16), 256, 0, stream>>>(x, wkv, KV, N_, C_, 2*C_);
    hchunk_k<<<dim3(4, NCH_, B_), 256, 0, stream>>>(KV, rids, CHK, CHV);
    hscan_k<<<dim3(128), 256, 0, stream>>>(CHK, CHV);
    hweights_k<<<dim3(2, NCH_, B_), 512, 0, stream>>>(CHK, KV, QV, rids, LGP);
    wfinal_k<<<dim3(8), 256, 0, stream>>>(LGP, WOUT);
    hmix_k<<<dim3(2, NCH_, B_), 512, 0, stream>>>(CHV, KV, rids, WOUT, gate, out);

    // q/k/v rule projections (+ fused RoPE on q,k)
    proj_k<<<dim3(N_), 256, 0, stream>>>(x, sin_,       sout,       rU,       rV,       rG,    rids, qb,   1);
    proj_k<<<dim3(N_), 256, 0, stream>>>(x, sin_+32768, sout+32768, rU+16384, rV+16384, rG+16, rids, kb,   1);
    proj_k<<<dim3(N_), 256, 0, stream>>>(x, sin_+65536, sout+65536, rU+32768, rV+32768, rG+32, rids, vbuf, 0);

    // causal attention (bf16 MFMA)
    attn_k<<<dim3(16, 32), 256, 0, stream>>>(qb, kb, vbuf, ctxb);

    // output rule projection, accumulated onto hier result
    proj_k<<<dim3(N_), 256, 0, stream>>>(ctxb, sin_+98304, sout+98304, rU+49152, rV+49152, rG+48, rids, out, 2);
}